// Round 12
// baseline (388.821 us; speedup 1.0000x reference)
//
#include <hip/hip_runtime.h>
#include <hip/hip_bf16.h>

// RGCN layer, MI355X — round 23 (second resubmit of the chunked pipeline;
// r21 = acquisition timeout, r22 = container-failed-twice; full fault audit
// clean — tile-list bounds, chunk guards, bit-packing, LDS sizes, memset
// coverage all verified; everything outside chunking is byte-identical to
// the clean-running r19. Precedent: r13's container-fail was infra and the
// identical resubmit passed. Third failure => abandon chunking.)
// Design: conv FETCH 80-112MB vs 15 ideal = t_buf stream cycling L3,
// evicting node_bf/Wt. FIX: chunk conv->reduce by g512-quarters (4 x ~41MB
// t_buf chunks, PLAIN stores): reduce chunk k reads L3-hot t_buf written by
// conv chunk k; node_bf stays resident. Per-chunk tile lists (bucket->chunk
// = g5/10); reduce chunks = 5120-dst ranges, 8 dsts/block.

#define N_NODES 20000
#define E_EDGES 640000
#define R_REL   65
#define NG5     40                  // ceil(20000/512)
#define NG128   157                 // ceil(20000/128)
#define NSLOT   (NG5 * R_REL * 4)   // 10400
#define NKEY5   (NG5 * R_REL)       // 2600
#define NB_RESID 313
#define CH_TILES 4096               // per-chunk tile list capacity
#define TM      128

typedef __attribute__((ext_vector_type(8))) short bf16x8;
typedef __attribute__((ext_vector_type(4))) float f32x4;
typedef __attribute__((ext_vector_type(4))) unsigned int u32x4;
typedef __attribute__((ext_vector_type(2))) unsigned int u32x2;

__device__ __forceinline__ unsigned short f2bf(float x) {
    union { float f; unsigned int u; } c; c.f = x;
    unsigned int b = c.u + 0x7fffu + ((c.u >> 16) & 1u);   // RTNE
    return (unsigned short)(b >> 16);
}
__device__ __forceinline__ float bf2f_lo(unsigned int u) {
    union { unsigned int u; float f; } c; c.u = u << 16; return c.f;
}
__device__ __forceinline__ float bf2f_hi(unsigned int u) {
    union { unsigned int u; float f; } c; c.u = u & 0xffff0000u; return c.f;
}
__device__ __forceinline__ void async16(const void* g, void* l) {
    __builtin_amdgcn_global_load_lds(
        (const __attribute__((address_space(1))) unsigned int*)g,
        (__attribute__((address_space(3))) unsigned int*)l, 16, 0, 0);
}
__device__ __forceinline__ int unperm(int p) {      // permuted pos -> true col
    return (p & 64) + ((p & 3) << 4) + ((p >> 2) & 15);
}

// ---------------- K1: basis GEMM || LDS hists || f32->bf16 cvt -------------
__global__ void k_prep1(const float* __restrict__ comp, const float* __restrict__ basis,
                        float* __restrict__ W32, const int* __restrict__ et,
                        const int* __restrict__ dstA, int* __restrict__ gh3,
                        int* __restrict__ gh2, const float* __restrict__ node_feats,
                        unsigned short* __restrict__ node_bf) {
    __shared__ int shbuf[15200];                    // 60.8 KB, aliased per-section
    int b = blockIdx.x, t = threadIdx.x;
    if (b < 320) {                                  // basis GEMM
        float* lc = (float*)shbuf;                  // 16*65 floats
        int r0 = (b >> 6) * 16;
        int col = (b & 63) * 256 + t;
        for (int j = t; j < 16 * 65; j += 256) {
            int rr = r0 + j / 65;
            lc[j] = (rr < R_REL) ? comp[rr * 65 + (j % 65)] : 0.f;
        }
        __syncthreads();
        float acc[16];
#pragma unroll
        for (int j = 0; j < 16; ++j) acc[j] = 0.f;
        for (int k = 0; k < 65; ++k) {
            float v = basis[k * 16384 + col];
#pragma unroll
            for (int j = 0; j < 16; ++j) acc[j] += lc[j * 65 + k] * v;
        }
#pragma unroll
        for (int j = 0; j < 16; ++j) {
            int rr = r0 + j;
            if (rr < R_REL) W32[rr * 16384 + col] = acc[j];
        }
    } else if (b < 384) {                           // LDS-packed histograms
        int* pk2 = shbuf;                           // 10000 ints (20000 dst ctrs)
        int* pk3 = shbuf + 10000;                   // 5200 ints (10400 slot ctrs)
        for (int i = t; i < 15200; i += 256) shbuf[i] = 0;
        __syncthreads();
        for (int i = (b - 320) * 256 + t; i < E_EDGES; i += 64 * 256) {
            int d = dstA[i];
            int slot = ((d >> 9) * 65 + et[i]) * 4 + ((d >> 7) & 3);
            atomicAdd(&pk2[d >> 1], (int)(1u << ((d & 1) << 4)));
            atomicAdd(&pk3[slot >> 1], (int)(1u << ((slot & 1) << 4)));
        }
        __syncthreads();
        for (int i = t; i < 10000; i += 256) {      // coalesced merge
            unsigned v = (unsigned)pk2[i];
            if (v & 0xffffu) atomicAdd(&gh2[2 * i], (int)(v & 0xffffu));
            if (v >> 16)     atomicAdd(&gh2[2 * i + 1], (int)(v >> 16));
        }
        for (int i = t; i < 5200; i += 256) {
            unsigned v = (unsigned)pk3[i];
            if (v & 0xffffu) atomicAdd(&gh3[2 * i], (int)(v & 0xffffu));
            if (v >> 16)     atomicAdd(&gh3[2 * i + 1], (int)(v >> 16));
        }
    } else {                                        // cvt fp32 -> bf16 (x4)
        int i = (b - 384) * 256 + t;
        if (i < N_NODES * 32) {
            float4 v = reinterpret_cast<const float4*>(node_feats)[i];
            __hip_bfloat162 b0 = __float22bfloat162_rn(make_float2(v.x, v.y));
            __hip_bfloat162 b1 = __float22bfloat162_rn(make_float2(v.z, v.w));
            u32x2 pk;
            pk.x = *reinterpret_cast<unsigned int*>(&b0);
            pk.y = *reinterpret_cast<unsigned int*>(&b1);
            reinterpret_cast<u32x2*>(node_bf)[i] = pk;
        }
    }
}

// ---------------- K2: slot scan || dst scan || W transposes ----------------
__global__ void k_prep3(const int* __restrict__ gh3, int* __restrict__ segAll,
                        const int* __restrict__ gh2, int* __restrict__ seg,
                        const float* __restrict__ W32, unsigned short* __restrict__ Wt,
                        const float* __restrict__ Wresf, unsigned short* __restrict__ Wrest) {
    int b = blockIdx.x, t = threadIdx.x;
    if (b < 41) {                                   // scan 10400 slots
        __shared__ int red[256];
        __shared__ int pref;
        int acc = 0;
        for (int i = t; i < b * 256; i += 256) acc += gh3[i];
        red[t] = acc;
        __syncthreads();
        for (int off = 128; off > 0; off >>= 1) {
            if (t < off) red[t] += red[t + off];
            __syncthreads();
        }
        if (t == 0) pref = red[0];
        __syncthreads();
        int i = b * 256 + t;
        int v = (i < NSLOT) ? gh3[i] : 0;
        red[t] = v;
        __syncthreads();
        for (int off = 1; off < 256; off <<= 1) {
            int x = (t >= off) ? red[t - off] : 0;
            __syncthreads();
            red[t] += x;
            __syncthreads();
        }
        int excl = red[t] - v + pref;
        if (i < NSLOT) {
            segAll[i] = excl;
            if (i == NSLOT - 1) segAll[NSLOT] = excl + v;
        }
    } else if (b < 120) {                           // scan 20000 dsts
        __shared__ int red[256];
        __shared__ int pref;
        int b2 = b - 41;
        int acc = 0;
        for (int i = t; i < b2 * 256; i += 256) acc += gh2[i];
        red[t] = acc;
        __syncthreads();
        for (int off = 128; off > 0; off >>= 1) {
            if (t < off) red[t] += red[t + off];
            __syncthreads();
        }
        if (t == 0) pref = red[0];
        __syncthreads();
        int i = b2 * 256 + t;
        int v = (i < N_NODES) ? gh2[i] : 0;
        red[t] = v;
        __syncthreads();
        for (int off = 1; off < 256; off <<= 1) {
            int x = (t >= off) ? red[t - off] : 0;
            __syncthreads();
            red[t] += x;
            __syncthreads();
        }
        int excl = red[t] - v + pref;
        if (i < N_NODES) {
            seg[i] = excl;
            if (i == N_NODES - 1) seg[N_NODES] = excl + v;
        }
    } else {                                        // transposes (264 blocks)
        __shared__ float tile[64][65];
        int bb = b - 120;
        const float* s; unsigned short* d; int sub;
        if (bb < R_REL * 4) { s = W32 + (size_t)(bb >> 2) * 16384; d = Wt + (size_t)(bb >> 2) * 16384; sub = bb & 3; }
        else { s = Wresf; d = Wrest; sub = bb - R_REL * 4; }
        int ot = (sub >> 1) & 1, itl = sub & 1;
        int tx = t & 63, ty = t >> 6;
        for (int it = 0; it < 16; ++it) {
            int i = ty + it * 4;
            tile[i][tx] = s[(itl * 64 + i) * 128 + ot * 64 + tx];
        }
        __syncthreads();
        for (int it = 0; it < 16; ++it) {
            int o = ty + it * 4;
            d[(ot * 64 + o) * 128 + itl * 64 + tx] = f2bf(tile[tx][o]);
        }
    }
}

// ---------------- K3a: pass A — sort edges by dst-group-128 ----------------
__global__ void k_scatterA(const int* __restrict__ et, const int* __restrict__ srcA,
                           const int* __restrict__ dstA, const float* __restrict__ norm,
                           const int* __restrict__ seg, int* __restrict__ cntA,
                           u32x2* __restrict__ ebuf) {
    __shared__ int lh[NG128], lbase[NG128];
    int c0 = blockIdx.x * 2560;
    int cend = min(c0 + 2560, E_EDGES);
    int t = threadIdx.x;
    for (int i = t; i < NG128; i += 256) lh[i] = 0;
    __syncthreads();
    for (int i = c0 + t; i < cend; i += 256) atomicAdd(&lh[dstA[i] >> 7], 1);
    __syncthreads();
    for (int i = t; i < NG128; i += 256)
        if (lh[i] > 0) lbase[i] = seg[i * 128] + atomicAdd(&cntA[i], lh[i]);
    __syncthreads();
    for (int i = t; i < NG128; i += 256) lh[i] = 0;
    __syncthreads();
    for (int i = c0 + t; i < cend; i += 256) {
        int d = dstA[i];
        int g = d >> 7;
        int p = lbase[g] + atomicAdd(&lh[g], 1);
        u32x2 e;
        e.x = (unsigned)srcA[i] | ((unsigned)(d & 127) << 15) | ((unsigned)et[i] << 22);
        e.y = __float_as_uint(norm[i]);
        ebuf[p] = e;
    }
}

// ---------------- K3b: pass B — within-group bucket sort + chunk tiles -----
__global__ void k_scatterB(const u32x2* __restrict__ ebuf, const int* __restrict__ seg,
                           const int* __restrict__ segAll, int* __restrict__ srcp,
                           float* __restrict__ normp, int* __restrict__ eidx,
                           int* __restrict__ ntiles4, int* __restrict__ tile_r,
                           int* __restrict__ tile_start, int* __restrict__ tile_len) {
    int b = blockIdx.x, t = threadIdx.x;
    if (b < NG128) {                                // one block per g128
        __shared__ int base65[R_REL], lcnt[R_REL], sdst[128], ldst[128];
        int g5 = b >> 2, sub = b & 3;
        if (t < R_REL) { base65[t] = segAll[(g5 * 65 + t) * 4 + sub]; lcnt[t] = 0; }
        if (t < 128) {
            int d = b * 128 + t;
            sdst[t] = seg[min(d, N_NODES)];
            ldst[t] = 0;
        }
        __syncthreads();
        int e0 = seg[b * 128];
        int e1 = seg[min((b + 1) * 128, N_NODES)];
        for (int i = e0 + t; i < e1; i += 1024) {
            u32x2 e = ebuf[i];
            int src = e.x & 0x7fff;
            int slot = (e.x >> 15) & 127;
            int rel = e.x >> 22;
            int p = base65[rel] + atomicAdd(&lcnt[rel], 1);
            srcp[p] = src;
            normp[p] = __uint_as_float(e.y);
            int pos = sdst[slot] + atomicAdd(&ldst[slot], 1);
            eidx[pos] = p;
        }
    } else {                                        // tile emission (3 blocks)
        int k2 = (b - NG128) * 1024 + t;
        if (k2 < NKEY5) {
            int s = segAll[k2 * 4], e = segAll[k2 * 4 + 4];
            int len = e - s;
            if (len > 0) {
                int c = (k2 / 65) / 10;             // chunk = g5/10
                int nt = (len + TM - 1) / TM;
                int base = atomicAdd(&ntiles4[c], nt);
                for (int kk = 0; kk < nt; ++kk) {
                    int j = c * CH_TILES + base + kk;
                    tile_r[j] = k2 % 65;
                    tile_start[j] = s + kk * TM;
                    tile_len[j] = min(TM, len - kk * TM);
                }
            }
        }
    }
}

// ---------------- K4: resid tiles (chunk 0) + 128-row edge GEMM tiles ------
__global__ __launch_bounds__(256, 2) void k_conv_gemm(
    const int* __restrict__ tile_r, const int* __restrict__ tile_start,
    const int* __restrict__ tile_len, const int* __restrict__ ntiles4,
    const int* __restrict__ srcp, const float* __restrict__ normp,
    const unsigned short* __restrict__ node_bf,
    const unsigned short* __restrict__ Wt, const unsigned short* __restrict__ Wrest,
    const float* __restrict__ b_res, unsigned short* __restrict__ t_out,
    float* __restrict__ resid, int chunk) {
    __shared__ unsigned short Alds[128 * 128];      // 32 KB
    __shared__ unsigned short Blds[128 * 128];      // 32 KB
    __shared__ float snorm[128];
    int t = threadIdx.x;
    int w = t >> 6, lane = t & 63;
    int lrow = lane & 15, quad = lane >> 4;

    int tid;
    if (chunk == 0) {
        if (blockIdx.x < NB_RESID) {
            // ---- residual tile: rows row0..row0+63, relu(x@W_res+b) -> resid
            int wr = (w >> 1) * 32, wc = (w & 1) * 64;
            int row0 = blockIdx.x * 64;
            int nrows = min(64, N_NODES - row0);
#pragma unroll
            for (int it = 0; it < 8; ++it) {
                int j = t + 256 * it;
                int o = j >> 4, c = j & 15, cs = c ^ (o & 15);
                async16(Wrest + o * 128 + cs * 8, &Blds[o * 128 + c * 8]);
            }
#pragma unroll
            for (int it = 0; it < 4; ++it) {
                int j = t + 256 * it;
                int p = j >> 4, c = j & 15, cs = c ^ (p & 15);
                if (p < nrows)
                    async16(node_bf + (size_t)(row0 + p) * 128 + cs * 8,
                            &Alds[p * 128 + c * 8]);
            }
            __syncthreads();
            f32x4 acc[2][4];
#pragma unroll
            for (int i = 0; i < 2; ++i)
#pragma unroll
                for (int j = 0; j < 4; ++j) acc[i][j] = (f32x4){0.f, 0.f, 0.f, 0.f};
#pragma unroll
            for (int ks = 0; ks < 4; ++ks) {
                int cs = (ks * 4 + quad) ^ lrow;
                bf16x8 af[2], bfr[4];
#pragma unroll
                for (int i = 0; i < 2; ++i)
                    af[i] = *reinterpret_cast<const bf16x8*>(&Alds[(wr + i * 16 + lrow) * 128 + cs * 8]);
#pragma unroll
                for (int j = 0; j < 4; ++j)
                    bfr[j] = *reinterpret_cast<const bf16x8*>(&Blds[(wc + j * 16 + lrow) * 128 + cs * 8]);
#pragma unroll
                for (int i = 0; i < 2; ++i)
#pragma unroll
                    for (int j = 0; j < 4; ++j)
                        acc[i][j] = __builtin_amdgcn_mfma_f32_16x16x32_bf16(af[i], bfr[j], acc[i][j], 0, 0, 0);
            }
            float br0 = b_res[wc + lrow];
            float br1 = b_res[wc + 16 + lrow];
            float br2 = b_res[wc + 32 + lrow];
            float br3 = b_res[wc + 48 + lrow];
#pragma unroll
            for (int i = 0; i < 2; ++i) {
#pragma unroll
                for (int reg = 0; reg < 4; ++reg) {
                    int grow = row0 + wr + i * 16 + quad * 4 + reg;
                    if (grow < N_NODES) {
                        float4 v;
                        v.x = fmaxf(acc[i][0][reg] + br0, 0.f);
                        v.y = fmaxf(acc[i][1][reg] + br1, 0.f);
                        v.z = fmaxf(acc[i][2][reg] + br2, 0.f);
                        v.w = fmaxf(acc[i][3][reg] + br3, 0.f);
                        *reinterpret_cast<float4*>(resid + (size_t)grow * 128 + wc + lrow * 4) = v;
                    }
                }
            }
            return;
        }
        tid = blockIdx.x - NB_RESID;
    } else {
        tid = blockIdx.x;
    }

    // ---- edge tile: 128 rows x 128 cols, wave w owns rows w*32..+31
    if (tid >= ntiles4[chunk]) return;
    int idx = chunk * CH_TILES + tid;
    int r = tile_r[idx], start = tile_start[idx], len = tile_len[idx];
    int wr = w * 32;
    const unsigned short* Wr = Wt + (size_t)r * 16384;
#pragma unroll
    for (int it = 0; it < 8; ++it) {               // stage W (XOR on source)
        int j = t + 256 * it;
        int o = j >> 4, c = j & 15, cs = c ^ (o & 15);
        async16(Wr + o * 128 + cs * 8, &Blds[o * 128 + c * 8]);
    }
#pragma unroll
    for (int it = 0; it < 8; ++it) {               // stage A (gathered rows)
        int j = t + 256 * it;
        int p = j >> 4, c = j & 15, cs = c ^ (p & 15);
        if (p < len)
            async16(node_bf + (size_t)srcp[start + p] * 128 + cs * 8,
                    &Alds[p * 128 + c * 8]);
    }
    if (t < TM && t < len) snorm[t] = normp[start + t];
    __syncthreads();

    f32x4 acc[2][8];
#pragma unroll
    for (int i = 0; i < 2; ++i)
#pragma unroll
        for (int j = 0; j < 8; ++j) acc[i][j] = (f32x4){0.f, 0.f, 0.f, 0.f};
#pragma unroll
    for (int ks = 0; ks < 4; ++ks) {
        int cs = (ks * 4 + quad) ^ lrow;
        bf16x8 af[2], bfr[8];
#pragma unroll
        for (int i = 0; i < 2; ++i)
            af[i] = *reinterpret_cast<const bf16x8*>(&Alds[(wr + i * 16 + lrow) * 128 + cs * 8]);
#pragma unroll
        for (int j = 0; j < 8; ++j)
            bfr[j] = *reinterpret_cast<const bf16x8*>(&Blds[(j * 16 + lrow) * 128 + cs * 8]);
#pragma unroll
        for (int i = 0; i < 2; ++i)
#pragma unroll
            for (int j = 0; j < 8; ++j)
                acc[i][j] = __builtin_amdgcn_mfma_f32_16x16x32_bf16(af[i], bfr[j], acc[i][j], 0, 0, 0);
    }

    // epilogue: scale by norm, pack bf16, PLAIN sequential full-line stores
    // (L3-resident chunk; reduce chunk reads it next).
#pragma unroll
    for (int i = 0; i < 2; ++i) {
        int m0 = wr + i * 16 + quad * 4;
#pragma unroll
        for (int reg = 0; reg < 4; ++reg) {
            int m = m0 + reg;
            if (m < len) {
                float nm = snorm[m];
                float2 l0 = make_float2(acc[i][0][reg] * nm, acc[i][1][reg] * nm);
                float2 l1 = make_float2(acc[i][2][reg] * nm, acc[i][3][reg] * nm);
                float2 h0 = make_float2(acc[i][4][reg] * nm, acc[i][5][reg] * nm);
                float2 h1 = make_float2(acc[i][6][reg] * nm, acc[i][7][reg] * nm);
                __hip_bfloat162 bl0 = __float22bfloat162_rn(l0);
                __hip_bfloat162 bl1 = __float22bfloat162_rn(l1);
                __hip_bfloat162 bh0 = __float22bfloat162_rn(h0);
                __hip_bfloat162 bh1 = __float22bfloat162_rn(h1);
                u32x2 s0, s1;
                s0.x = *reinterpret_cast<unsigned int*>(&bl0);
                s0.y = *reinterpret_cast<unsigned int*>(&bl1);
                s1.x = *reinterpret_cast<unsigned int*>(&bh0);
                s1.y = *reinterpret_cast<unsigned int*>(&bh1);
                unsigned short* rowp = t_out + (size_t)(start + m) * 128;
                *reinterpret_cast<u32x2*>(rowp + lrow * 4)      = s0;
                *reinterpret_cast<u32x2*>(rowp + 64 + lrow * 4) = s1;
            }
        }
    }
}

// ---------------- K5: chunked wave-per-dst reduce via eidx -----------------
__global__ __launch_bounds__(256) void k_reduce_fused(
    const unsigned short* __restrict__ t, const int* __restrict__ seg,
    const int* __restrict__ eidx, const float* __restrict__ resid,
    const float* __restrict__ h_bias, float* __restrict__ h,
    float* __restrict__ colsum, float* __restrict__ colsumsq, int chunk) {
    __shared__ float cs1[128], cs2[128], sbias[128];
    if (threadIdx.x < 128) {
        cs1[threadIdx.x] = 0.f; cs2[threadIdx.x] = 0.f;
        sbias[threadIdx.x] = h_bias[unperm(threadIdx.x)];
    }
    __syncthreads();
    int w = threadIdx.x >> 6, lane = threadIdx.x & 63;
    int g = lane >> 4, c = lane & 15;
    for (int k = 0; k < 2; ++k) {
        int d = chunk * 5120 + blockIdx.x * 8 + k * 4 + w;
        if (d >= N_NODES) continue;
        int a = seg[d], b = seg[d + 1];
        float s[8];
#pragma unroll
        for (int kk = 0; kk < 8; ++kk) s[kk] = 0.f;
        for (int q = a + g; q < b; q += 32) {
            int er[8];
#pragma unroll
            for (int kk = 0; kk < 8; ++kk) {
                int row = q + 4 * kk;
                er[kk] = eidx[(row < b) ? row : a];
            }
            u32x4 v[8];
#pragma unroll
            for (int kk = 0; kk < 8; ++kk) {
                v[kk] = *reinterpret_cast<const u32x4*>(t + (size_t)er[kk] * 128 + c * 8);
                if (q + 4 * kk >= b) v[kk] = (u32x4){0u, 0u, 0u, 0u};
            }
#pragma unroll
            for (int kk = 0; kk < 8; ++kk)
#pragma unroll
                for (int j = 0; j < 4; ++j) {
                    s[2 * j]     += bf2f_lo(v[kk][j]);
                    s[2 * j + 1] += bf2f_hi(v[kk][j]);
                }
        }
#pragma unroll
        for (int kk = 0; kk < 8; ++kk) {
            s[kk] += __shfl_xor(s[kk], 16);
            s[kk] += __shfl_xor(s[kk], 32);
        }
        if (g == 0) {
            const float* rp = resid + (size_t)d * 128 + c * 8;
            float4 r0 = *reinterpret_cast<const float4*>(rp);
            float4 r1 = *reinterpret_cast<const float4*>(rp + 4);
            float rr[8] = {r0.x, r0.y, r0.z, r0.w, r1.x, r1.y, r1.z, r1.w};
            float v[8];
#pragma unroll
            for (int kk = 0; kk < 8; ++kk)
                v[kk] = fmaxf(s[kk] + sbias[c * 8 + kk], 0.f) + rr[kk];
            float* hp = h + (size_t)d * 128 + c * 8;
            *reinterpret_cast<float4*>(hp)     = make_float4(v[0], v[1], v[2], v[3]);
            *reinterpret_cast<float4*>(hp + 4) = make_float4(v[4], v[5], v[6], v[7]);
#pragma unroll
            for (int kk = 0; kk < 8; ++kk) {
                atomicAdd(&cs1[c * 8 + kk], v[kk]);
                atomicAdd(&cs2[c * 8 + kk], v[kk] * v[kk]);
            }
        }
    }
    __syncthreads();
    if (threadIdx.x < 128) {
        atomicAdd(&colsum[threadIdx.x], cs1[threadIdx.x]);
        atomicAdd(&colsumsq[threadIdx.x], cs2[threadIdx.x]);
    }
}

// ---------------- K6: BN apply + unpermute to natural cols -----------------
__global__ void k_bn(float* __restrict__ h, const float* __restrict__ colsum,
                     const float* __restrict__ colsumsq, const float* __restrict__ gamma,
                     const float* __restrict__ beta) {
    __shared__ float sc[128], sh[128], tile[8][128];
    int t = threadIdx.x;
    if (t < 128) {
        int n = unperm(t);
        float m = colsum[t] * (1.f / N_NODES);
        float var = colsumsq[t] * (1.f / N_NODES) - m * m;
        float s = gamma[n] * rsqrtf(var + 1e-5f);
        sc[t] = s;
        sh[t] = beta[n] - m * s;
    }
    __syncthreads();
    int r = t >> 5;
    int p0 = (t & 31) * 4;
    int n0 = (p0 & 64) + ((p0 >> 2) & 15);
    for (int row0 = blockIdx.x * 8; row0 < N_NODES; row0 += gridDim.x * 8) {
        int row = row0 + r;
        float4 v = make_float4(0.f, 0.f, 0.f, 0.f);
        if (row < N_NODES) v = *reinterpret_cast<float4*>(h + (size_t)row * 128 + p0);
        v.x = v.x * sc[p0] + sh[p0];
        v.y = v.y * sc[p0 + 1] + sh[p0 + 1];
        v.z = v.z * sc[p0 + 2] + sh[p0 + 2];
        v.w = v.w * sc[p0 + 3] + sh[p0 + 3];
        tile[r][n0]      = v.x;
        tile[r][n0 + 16] = v.y;
        tile[r][n0 + 32] = v.z;
        tile[r][n0 + 48] = v.w;
        __syncthreads();
        if (row < N_NODES)
            *reinterpret_cast<float4*>(h + (size_t)row * 128 + p0) =
                *reinterpret_cast<float4*>(&tile[r][p0]);
        __syncthreads();
    }
}

extern "C" void kernel_launch(void* const* d_in, const int* in_sizes, int n_in,
                              void* d_out, int out_size, void* d_ws, size_t ws_size,
                              hipStream_t stream) {
    (void)in_sizes; (void)n_in; (void)out_size; (void)ws_size;
    const float* node_feats = (const float*)d_in[0];
    const int* src    = (const int*)d_in[1];
    const int* dst    = (const int*)d_in[2];
    const int* etype  = (const int*)d_in[3];
    const float* norm = (const float*)d_in[4];
    const float* basis = (const float*)d_in[5];
    const float* comp  = (const float*)d_in[6];
    const float* h_bias = (const float*)d_in[7];
    const float* W_res  = (const float*)d_in[8];
    const float* b_res  = (const float*)d_in[9];
    const float* gamma  = (const float*)d_in[10];
    const float* beta   = (const float*)d_in[11];

    char* ws = (char*)d_ws;
    float* colsum   = (float*)(ws + 0);            // 512
    float* colsumsq = (float*)(ws + 512);          // 512
    int* ntiles4    = (int*)(ws + 1024);           // 16
    int* cntA       = (int*)(ws + 1088);           // 628 -> pad 1792
    int* gh3        = (int*)(ws + 1792);           // 41600 -> 43392
    int* gh2        = (int*)(ws + 43392);          // 80000 -> 123392 [memset end]
    int* segAll     = (int*)(ws + 123392);         // 41604 -> 164996 pad 165056
    int* seg        = (int*)(ws + 165056);         // 80004 -> 245060 pad 245120
    int* tile_r     = (int*)(ws + 245120);         // 65536 -> 310656
    int* tile_start = (int*)(ws + 310656);         // 65536 -> 376192
    int* tile_len   = (int*)(ws + 376192);         // 65536 -> 441728
    unsigned short* Wt      = (unsigned short*)(ws + 441728);    // 2129920 -> 2571648
    unsigned short* Wrest   = (unsigned short*)(ws + 2571648);   // 32768   -> 2604416
    unsigned short* node_bf = (unsigned short*)(ws + 2604416);   // 5120000 -> 7724416
    int* srcp       = (int*)(ws + 7724416);        // 2560000 -> 10284416
    float* normp    = (float*)(ws + 10284416);     // 2560000 -> 12844416
    int* eidx       = (int*)(ws + 12844416);       // 2560000 -> 15404416
    u32x2* ebuf     = (u32x2*)(ws + 15404416);     // 5120000 -> 20524416
    float* resid    = (float*)(ws + 20524416);     // 10240000 -> 30764416
    const long T_BASE = 30764416L;                 // 16B aligned
    float* W32      = (float*)(ws + T_BASE);       // aliased: dead before conv
    unsigned short* t_buf = (unsigned short*)(ws + T_BASE);      // 163.84 MB
    float* hacc = (float*)d_out;

    hipMemsetAsync(ws, 0, 123392, stream);         // colsum..gh2
    k_prep1<<<2884, 256, 0, stream>>>(comp, basis, W32, etype, dst, gh3, gh2,
                                      node_feats, node_bf);
    k_prep3<<<384, 256, 0, stream>>>(gh3, segAll, gh2, seg, W32, Wt, W_res, Wrest);
    k_scatterA<<<250, 256, 0, stream>>>(etype, src, dst, norm, seg, cntA, ebuf);
    k_scatterB<<<160, 1024, 0, stream>>>(ebuf, seg, segAll, srcp, normp, eidx,
                                         ntiles4, tile_r, tile_start, tile_len);
    for (int c = 0; c < 4; ++c) {
        k_conv_gemm<<<(c == 0 ? NB_RESID : 0) + CH_TILES, 256, 0, stream>>>(
            tile_r, tile_start, tile_len, ntiles4, srcp, normp, node_bf,
            Wt, Wrest, b_res, t_buf, resid, c);
        k_reduce_fused<<<640, 256, 0, stream>>>(t_buf, seg, eidx, resid,
                                                h_bias, hacc, colsum, colsumsq, c);
    }
    k_bn<<<2500, 256, 0, stream>>>(hacc, colsum, colsumsq, gamma, beta);
}

// Round 13
// 285.615 us; speedup vs baseline: 1.3613x; 1.3613x over previous
//
#include <hip/hip_runtime.h>
#include <hip/hip_bf16.h>

// RGCN layer, MI355X — round 24. REVERT chunking (r23: 388us, 8 serialized
// small launches pay ramp+tail each; fills showed 6.6TB/s @ 8% occupancy so
// occupancy isn't conv's limit — the barrier-drained staging chain is).
// Base = r19 (291.8 best). NEW: A-tile has ZERO cross-wave sharing (wave w
// owns rows w*32..+31) -> LDS staging of A is a pure round trip. A goes
// direct-to-register: 2 srcp loads + 8x16B global loads per lane, issued
// BEFORE the W barrier (A latency hides under W staging; unlike r20's
// failed W-from-global these are few, early, and have no LDS-sharing
// benefit to lose). Alds deleted: LDS 66->33KB, launch_bounds(256,3).
// Resid branch same treatment. Reduce: 626 -> 2500 blocks (tail shape).

#define N_NODES 20000
#define E_EDGES 640000
#define R_REL   65
#define NG5     40                  // ceil(20000/512)
#define NG128   157                 // ceil(20000/128)
#define NSLOT   (NG5 * R_REL * 4)   // 10400
#define NKEY5   (NG5 * R_REL)       // 2600
#define NB_RESID 313
#define MAX_TILES 10240
#define TM      128

typedef __attribute__((ext_vector_type(8))) short bf16x8;
typedef __attribute__((ext_vector_type(4))) float f32x4;
typedef __attribute__((ext_vector_type(4))) unsigned int u32x4;
typedef __attribute__((ext_vector_type(2))) unsigned int u32x2;

__device__ __forceinline__ unsigned short f2bf(float x) {
    union { float f; unsigned int u; } c; c.f = x;
    unsigned int b = c.u + 0x7fffu + ((c.u >> 16) & 1u);   // RTNE
    return (unsigned short)(b >> 16);
}
__device__ __forceinline__ float bf2f_lo(unsigned int u) {
    union { unsigned int u; float f; } c; c.u = u << 16; return c.f;
}
__device__ __forceinline__ float bf2f_hi(unsigned int u) {
    union { unsigned int u; float f; } c; c.u = u & 0xffff0000u; return c.f;
}
__device__ __forceinline__ void async16(const void* g, void* l) {
    __builtin_amdgcn_global_load_lds(
        (const __attribute__((address_space(1))) unsigned int*)g,
        (__attribute__((address_space(3))) unsigned int*)l, 16, 0, 0);
}
__device__ __forceinline__ int unperm(int p) {      // permuted pos -> true col
    return (p & 64) + ((p & 3) << 4) + ((p >> 2) & 15);
}

// ---------------- K1: basis GEMM || LDS hists || f32->bf16 cvt -------------
__global__ void k_prep1(const float* __restrict__ comp, const float* __restrict__ basis,
                        float* __restrict__ W32, const int* __restrict__ et,
                        const int* __restrict__ dstA, int* __restrict__ gh3,
                        int* __restrict__ gh2, const float* __restrict__ node_feats,
                        unsigned short* __restrict__ node_bf) {
    __shared__ int shbuf[15200];                    // 60.8 KB, aliased per-section
    int b = blockIdx.x, t = threadIdx.x;
    if (b < 320) {                                  // basis GEMM
        float* lc = (float*)shbuf;                  // 16*65 floats
        int r0 = (b >> 6) * 16;
        int col = (b & 63) * 256 + t;
        for (int j = t; j < 16 * 65; j += 256) {
            int rr = r0 + j / 65;
            lc[j] = (rr < R_REL) ? comp[rr * 65 + (j % 65)] : 0.f;
        }
        __syncthreads();
        float acc[16];
#pragma unroll
        for (int j = 0; j < 16; ++j) acc[j] = 0.f;
        for (int k = 0; k < 65; ++k) {
            float v = basis[k * 16384 + col];
#pragma unroll
            for (int j = 0; j < 16; ++j) acc[j] += lc[j * 65 + k] * v;
        }
#pragma unroll
        for (int j = 0; j < 16; ++j) {
            int rr = r0 + j;
            if (rr < R_REL) W32[rr * 16384 + col] = acc[j];
        }
    } else if (b < 384) {                           // LDS-packed histograms
        int* pk2 = shbuf;                           // 10000 ints (20000 dst ctrs)
        int* pk3 = shbuf + 10000;                   // 5200 ints (10400 slot ctrs)
        for (int i = t; i < 15200; i += 256) shbuf[i] = 0;
        __syncthreads();
        for (int i = (b - 320) * 256 + t; i < E_EDGES; i += 64 * 256) {
            int d = dstA[i];
            int slot = ((d >> 9) * 65 + et[i]) * 4 + ((d >> 7) & 3);
            atomicAdd(&pk2[d >> 1], (int)(1u << ((d & 1) << 4)));
            atomicAdd(&pk3[slot >> 1], (int)(1u << ((slot & 1) << 4)));
        }
        __syncthreads();
        for (int i = t; i < 10000; i += 256) {      // coalesced merge
            unsigned v = (unsigned)pk2[i];
            if (v & 0xffffu) atomicAdd(&gh2[2 * i], (int)(v & 0xffffu));
            if (v >> 16)     atomicAdd(&gh2[2 * i + 1], (int)(v >> 16));
        }
        for (int i = t; i < 5200; i += 256) {
            unsigned v = (unsigned)pk3[i];
            if (v & 0xffffu) atomicAdd(&gh3[2 * i], (int)(v & 0xffffu));
            if (v >> 16)     atomicAdd(&gh3[2 * i + 1], (int)(v >> 16));
        }
    } else {                                        // cvt fp32 -> bf16 (x4)
        int i = (b - 384) * 256 + t;
        if (i < N_NODES * 32) {
            float4 v = reinterpret_cast<const float4*>(node_feats)[i];
            __hip_bfloat162 b0 = __float22bfloat162_rn(make_float2(v.x, v.y));
            __hip_bfloat162 b1 = __float22bfloat162_rn(make_float2(v.z, v.w));
            u32x2 pk;
            pk.x = *reinterpret_cast<unsigned int*>(&b0);
            pk.y = *reinterpret_cast<unsigned int*>(&b1);
            reinterpret_cast<u32x2*>(node_bf)[i] = pk;
        }
    }
}

// ---------------- K2: slot scan || dst scan || W transposes ----------------
__global__ void k_prep3(const int* __restrict__ gh3, int* __restrict__ segAll,
                        const int* __restrict__ gh2, int* __restrict__ seg,
                        const float* __restrict__ W32, unsigned short* __restrict__ Wt,
                        const float* __restrict__ Wresf, unsigned short* __restrict__ Wrest) {
    int b = blockIdx.x, t = threadIdx.x;
    if (b < 41) {                                   // scan 10400 slots
        __shared__ int red[256];
        __shared__ int pref;
        int acc = 0;
        for (int i = t; i < b * 256; i += 256) acc += gh3[i];
        red[t] = acc;
        __syncthreads();
        for (int off = 128; off > 0; off >>= 1) {
            if (t < off) red[t] += red[t + off];
            __syncthreads();
        }
        if (t == 0) pref = red[0];
        __syncthreads();
        int i = b * 256 + t;
        int v = (i < NSLOT) ? gh3[i] : 0;
        red[t] = v;
        __syncthreads();
        for (int off = 1; off < 256; off <<= 1) {
            int x = (t >= off) ? red[t - off] : 0;
            __syncthreads();
            red[t] += x;
            __syncthreads();
        }
        int excl = red[t] - v + pref;
        if (i < NSLOT) {
            segAll[i] = excl;
            if (i == NSLOT - 1) segAll[NSLOT] = excl + v;
        }
    } else if (b < 120) {                           // scan 20000 dsts
        __shared__ int red[256];
        __shared__ int pref;
        int b2 = b - 41;
        int acc = 0;
        for (int i = t; i < b2 * 256; i += 256) acc += gh2[i];
        red[t] = acc;
        __syncthreads();
        for (int off = 128; off > 0; off >>= 1) {
            if (t < off) red[t] += red[t + off];
            __syncthreads();
        }
        if (t == 0) pref = red[0];
        __syncthreads();
        int i = b2 * 256 + t;
        int v = (i < N_NODES) ? gh2[i] : 0;
        red[t] = v;
        __syncthreads();
        for (int off = 1; off < 256; off <<= 1) {
            int x = (t >= off) ? red[t - off] : 0;
            __syncthreads();
            red[t] += x;
            __syncthreads();
        }
        int excl = red[t] - v + pref;
        if (i < N_NODES) {
            seg[i] = excl;
            if (i == N_NODES - 1) seg[N_NODES] = excl + v;
        }
    } else {                                        // transposes (264 blocks)
        __shared__ float tile[64][65];
        int bb = b - 120;
        const float* s; unsigned short* d; int sub;
        if (bb < R_REL * 4) { s = W32 + (size_t)(bb >> 2) * 16384; d = Wt + (size_t)(bb >> 2) * 16384; sub = bb & 3; }
        else { s = Wresf; d = Wrest; sub = bb - R_REL * 4; }
        int ot = (sub >> 1) & 1, itl = sub & 1;
        int tx = t & 63, ty = t >> 6;
        for (int it = 0; it < 16; ++it) {
            int i = ty + it * 4;
            tile[i][tx] = s[(itl * 64 + i) * 128 + ot * 64 + tx];
        }
        __syncthreads();
        for (int it = 0; it < 16; ++it) {
            int o = ty + it * 4;
            d[(ot * 64 + o) * 128 + itl * 64 + tx] = f2bf(tile[tx][o]);
        }
    }
}

// ---------------- K3a: pass A — sort edges by dst-group-128 ----------------
__global__ void k_scatterA(const int* __restrict__ et, const int* __restrict__ srcA,
                           const int* __restrict__ dstA, const float* __restrict__ norm,
                           const int* __restrict__ seg, int* __restrict__ cntA,
                           u32x2* __restrict__ ebuf) {
    __shared__ int lh[NG128], lbase[NG128];
    int c0 = blockIdx.x * 2560;
    int cend = min(c0 + 2560, E_EDGES);
    int t = threadIdx.x;
    for (int i = t; i < NG128; i += 256) lh[i] = 0;
    __syncthreads();
    for (int i = c0 + t; i < cend; i += 256) atomicAdd(&lh[dstA[i] >> 7], 1);
    __syncthreads();
    for (int i = t; i < NG128; i += 256)
        if (lh[i] > 0) lbase[i] = seg[i * 128] + atomicAdd(&cntA[i], lh[i]);
    __syncthreads();
    for (int i = t; i < NG128; i += 256) lh[i] = 0;
    __syncthreads();
    for (int i = c0 + t; i < cend; i += 256) {
        int d = dstA[i];
        int g = d >> 7;
        int p = lbase[g] + atomicAdd(&lh[g], 1);
        u32x2 e;
        e.x = (unsigned)srcA[i] | ((unsigned)(d & 127) << 15) | ((unsigned)et[i] << 22);
        e.y = __float_as_uint(norm[i]);
        ebuf[p] = e;
    }
}

// ---------------- K3b: pass B — within-group bucket sort + tiles -----------
__global__ void k_scatterB(const u32x2* __restrict__ ebuf, const int* __restrict__ seg,
                           const int* __restrict__ segAll, int* __restrict__ srcp,
                           float* __restrict__ normp, int* __restrict__ eidx,
                           int* __restrict__ ntiles_p, int* __restrict__ tile_r,
                           int* __restrict__ tile_start, int* __restrict__ tile_len) {
    int b = blockIdx.x, t = threadIdx.x;
    if (b < NG128) {                                // one block per g128
        __shared__ int base65[R_REL], lcnt[R_REL], sdst[128], ldst[128];
        int g5 = b >> 2, sub = b & 3;
        if (t < R_REL) { base65[t] = segAll[(g5 * 65 + t) * 4 + sub]; lcnt[t] = 0; }
        if (t < 128) {
            int d = b * 128 + t;
            sdst[t] = seg[min(d, N_NODES)];
            ldst[t] = 0;
        }
        __syncthreads();
        int e0 = seg[b * 128];
        int e1 = seg[min((b + 1) * 128, N_NODES)];
        for (int i = e0 + t; i < e1; i += 1024) {
            u32x2 e = ebuf[i];
            int src = e.x & 0x7fff;
            int slot = (e.x >> 15) & 127;
            int rel = e.x >> 22;
            int p = base65[rel] + atomicAdd(&lcnt[rel], 1);
            srcp[p] = src;
            normp[p] = __uint_as_float(e.y);
            int pos = sdst[slot] + atomicAdd(&ldst[slot], 1);
            eidx[pos] = p;
        }
    } else {                                        // tile emission (3 blocks)
        int k2 = (b - NG128) * 1024 + t;
        if (k2 < NKEY5) {
            int s = segAll[k2 * 4], e = segAll[k2 * 4 + 4];
            int len = e - s;
            if (len > 0) {
                int nt = (len + TM - 1) / TM;
                int base = atomicAdd(ntiles_p, nt);
                for (int k = 0; k < nt; ++k) {
                    tile_r[base + k] = k2 % 65;
                    tile_start[base + k] = s + k * TM;
                    tile_len[base + k] = min(TM, len - k * TM);
                }
            }
        }
    }
}

// ---------------- K4: resid tiles + edge GEMM; A direct-to-register --------
__global__ __launch_bounds__(256, 3) void k_conv_gemm(
    const int* __restrict__ tile_r, const int* __restrict__ tile_start,
    const int* __restrict__ tile_len, const int* __restrict__ ntiles_p,
    const int* __restrict__ srcp, const float* __restrict__ normp,
    const unsigned short* __restrict__ node_bf,
    const unsigned short* __restrict__ Wt, const unsigned short* __restrict__ Wrest,
    const float* __restrict__ b_res, unsigned short* __restrict__ t_out,
    float* __restrict__ resid) {
    __shared__ unsigned short Blds[128 * 128];      // 32 KB (W only)
    __shared__ float snorm[128];
    int t = threadIdx.x;
    int w = t >> 6, lane = t & 63;
    int lrow = lane & 15, quad = lane >> 4;

    if (blockIdx.x < NB_RESID) {
        // ---- residual tile: rows row0..row0+63, relu(x@W_res+b) -> resid
        int wr = (w >> 1) * 32, wc = (w & 1) * 64;
        int row0 = blockIdx.x * 64;
        int nrows = min(64, N_NODES - row0);
        // A direct-to-reg: lane owns rows wr+lrow, wr+16+lrow (contiguous src)
        int r0i = wr + lrow, r1i = wr + 16 + lrow;
        const bf16x8* a0p = reinterpret_cast<const bf16x8*>(
            node_bf + (size_t)(row0 + ((r0i < nrows) ? r0i : 0)) * 128);
        const bf16x8* a1p = reinterpret_cast<const bf16x8*>(
            node_bf + (size_t)(row0 + ((r1i < nrows) ? r1i : 0)) * 128);
        bf16x8 areg[2][4];
#pragma unroll
        for (int ks = 0; ks < 4; ++ks) {
            int cq = ks * 4 + quad;
            areg[0][ks] = a0p[cq];
            areg[1][ks] = a1p[cq];
        }
#pragma unroll
        for (int it = 0; it < 8; ++it) {            // stage Wrest (XOR on source)
            int j = t + 256 * it;
            int o = j >> 4, c = j & 15, cs = c ^ (o & 15);
            async16(Wrest + o * 128 + cs * 8, &Blds[o * 128 + c * 8]);
        }
        __syncthreads();
        f32x4 acc[2][4];
#pragma unroll
        for (int i = 0; i < 2; ++i)
#pragma unroll
            for (int j = 0; j < 4; ++j) acc[i][j] = (f32x4){0.f, 0.f, 0.f, 0.f};
#pragma unroll
        for (int ks = 0; ks < 4; ++ks) {
            int cs = (ks * 4 + quad) ^ lrow;
            bf16x8 bfr[4];
#pragma unroll
            for (int j = 0; j < 4; ++j)
                bfr[j] = *reinterpret_cast<const bf16x8*>(&Blds[(wc + j * 16 + lrow) * 128 + cs * 8]);
#pragma unroll
            for (int i = 0; i < 2; ++i)
#pragma unroll
                for (int j = 0; j < 4; ++j)
                    acc[i][j] = __builtin_amdgcn_mfma_f32_16x16x32_bf16(areg[i][ks], bfr[j], acc[i][j], 0, 0, 0);
        }
        float br0 = b_res[wc + lrow];
        float br1 = b_res[wc + 16 + lrow];
        float br2 = b_res[wc + 32 + lrow];
        float br3 = b_res[wc + 48 + lrow];
#pragma unroll
        for (int i = 0; i < 2; ++i) {
#pragma unroll
            for (int reg = 0; reg < 4; ++reg) {
                int grow = row0 + wr + i * 16 + quad * 4 + reg;
                if (grow < N_NODES) {
                    float4 v;
                    v.x = fmaxf(acc[i][0][reg] + br0, 0.f);
                    v.y = fmaxf(acc[i][1][reg] + br1, 0.f);
                    v.z = fmaxf(acc[i][2][reg] + br2, 0.f);
                    v.w = fmaxf(acc[i][3][reg] + br3, 0.f);
                    *reinterpret_cast<float4*>(resid + (size_t)grow * 128 + wc + lrow * 4) = v;
                }
            }
        }
        return;
    }

    // ---- edge tile: 128 rows x 128 cols, wave w owns rows w*32..+31
    int tid = blockIdx.x - NB_RESID;
    if (tid >= *ntiles_p) return;
    int r = tile_r[tid], start = tile_start[tid], len = tile_len[tid];
    int wr = w * 32;
    // A direct-to-reg: lane owns rows wr+lrow, wr+16+lrow (gathered)
    int r0i = wr + lrow, r1i = wr + 16 + lrow;
    int s0 = srcp[start + ((r0i < len) ? r0i : 0)];
    int s1 = srcp[start + ((r1i < len) ? r1i : 0)];
    const bf16x8* a0p = reinterpret_cast<const bf16x8*>(node_bf + (size_t)s0 * 128);
    const bf16x8* a1p = reinterpret_cast<const bf16x8*>(node_bf + (size_t)s1 * 128);
    bf16x8 areg[2][4];
#pragma unroll
    for (int ks = 0; ks < 4; ++ks) {
        int cq = ks * 4 + quad;
        areg[0][ks] = a0p[cq];
        areg[1][ks] = a1p[cq];
    }
    const unsigned short* Wr = Wt + (size_t)r * 16384;
#pragma unroll
    for (int it = 0; it < 8; ++it) {               // stage W (XOR on source)
        int j = t + 256 * it;
        int o = j >> 4, c = j & 15, cs = c ^ (o & 15);
        async16(Wr + o * 128 + cs * 8, &Blds[o * 128 + c * 8]);
    }
    if (t < TM && t < len) snorm[t] = normp[start + t];
    __syncthreads();

    f32x4 acc[2][8];
#pragma unroll
    for (int i = 0; i < 2; ++i)
#pragma unroll
        for (int j = 0; j < 8; ++j) acc[i][j] = (f32x4){0.f, 0.f, 0.f, 0.f};
#pragma unroll
    for (int ks = 0; ks < 4; ++ks) {
        int cs = (ks * 4 + quad) ^ lrow;
        bf16x8 bfr[8];
#pragma unroll
        for (int j = 0; j < 8; ++j)
            bfr[j] = *reinterpret_cast<const bf16x8*>(&Blds[(j * 16 + lrow) * 128 + cs * 8]);
#pragma unroll
        for (int i = 0; i < 2; ++i)
#pragma unroll
            for (int j = 0; j < 8; ++j)
                acc[i][j] = __builtin_amdgcn_mfma_f32_16x16x32_bf16(areg[i][ks], bfr[j], acc[i][j], 0, 0, 0);
    }

    // epilogue: scale by norm, pack bf16, NON-TEMPORAL sequential stores.
#pragma unroll
    for (int i = 0; i < 2; ++i) {
        int m0 = wr + i * 16 + quad * 4;
#pragma unroll
        for (int reg = 0; reg < 4; ++reg) {
            int m = m0 + reg;
            if (m < len) {
                float nm = snorm[m];
                float2 l0 = make_float2(acc[i][0][reg] * nm, acc[i][1][reg] * nm);
                float2 l1 = make_float2(acc[i][2][reg] * nm, acc[i][3][reg] * nm);
                float2 h0 = make_float2(acc[i][4][reg] * nm, acc[i][5][reg] * nm);
                float2 h1 = make_float2(acc[i][6][reg] * nm, acc[i][7][reg] * nm);
                __hip_bfloat162 bl0 = __float22bfloat162_rn(l0);
                __hip_bfloat162 bl1 = __float22bfloat162_rn(l1);
                __hip_bfloat162 bh0 = __float22bfloat162_rn(h0);
                __hip_bfloat162 bh1 = __float22bfloat162_rn(h1);
                u32x2 s0v, s1v;
                s0v.x = *reinterpret_cast<unsigned int*>(&bl0);
                s0v.y = *reinterpret_cast<unsigned int*>(&bl1);
                s1v.x = *reinterpret_cast<unsigned int*>(&bh0);
                s1v.y = *reinterpret_cast<unsigned int*>(&bh1);
                unsigned short* rowp = t_out + (size_t)(start + m) * 128;
                __builtin_nontemporal_store(s0v, reinterpret_cast<u32x2*>(rowp + lrow * 4));
                __builtin_nontemporal_store(s1v, reinterpret_cast<u32x2*>(rowp + 64 + lrow * 4));
            }
        }
    }
}

// ---------------- K5: wave-per-dst reduce via eidx (L2-local gather) -------
__global__ __launch_bounds__(256) void k_reduce_fused(
    const unsigned short* __restrict__ t, const int* __restrict__ seg,
    const int* __restrict__ eidx, const float* __restrict__ resid,
    const float* __restrict__ h_bias, float* __restrict__ h,
    float* __restrict__ colsum, float* __restrict__ colsumsq) {
    __shared__ float cs1[128], cs2[128], sbias[128];
    if (threadIdx.x < 128) {
        cs1[threadIdx.x] = 0.f; cs2[threadIdx.x] = 0.f;
        sbias[threadIdx.x] = h_bias[unperm(threadIdx.x)];
    }
    __syncthreads();
    int w = threadIdx.x >> 6, lane = threadIdx.x & 63;
    int g = lane >> 4, c = lane & 15;
    for (int k = 0; k < 2; ++k) {
        int d = blockIdx.x * 8 + k * 4 + w;
        if (d >= N_NODES) continue;
        int a = seg[d], b = seg[d + 1];
        float s[8];
#pragma unroll
        for (int kk = 0; kk < 8; ++kk) s[kk] = 0.f;
        for (int q = a + g; q < b; q += 32) {
            int er[8];
#pragma unroll
            for (int kk = 0; kk < 8; ++kk) {
                int row = q + 4 * kk;
                er[kk] = eidx[(row < b) ? row : a];
            }
            u32x4 v[8];
#pragma unroll
            for (int kk = 0; kk < 8; ++kk) {
                v[kk] = *reinterpret_cast<const u32x4*>(t + (size_t)er[kk] * 128 + c * 8);
                if (q + 4 * kk >= b) v[kk] = (u32x4){0u, 0u, 0u, 0u};
            }
#pragma unroll
            for (int kk = 0; kk < 8; ++kk)
#pragma unroll
                for (int j = 0; j < 4; ++j) {
                    s[2 * j]     += bf2f_lo(v[kk][j]);
                    s[2 * j + 1] += bf2f_hi(v[kk][j]);
                }
        }
#pragma unroll
        for (int kk = 0; kk < 8; ++kk) {
            s[kk] += __shfl_xor(s[kk], 16);
            s[kk] += __shfl_xor(s[kk], 32);
        }
        if (g == 0) {
            const float* rp = resid + (size_t)d * 128 + c * 8;
            float4 r0 = *reinterpret_cast<const float4*>(rp);
            float4 r1 = *reinterpret_cast<const float4*>(rp + 4);
            float rr[8] = {r0.x, r0.y, r0.z, r0.w, r1.x, r1.y, r1.z, r1.w};
            float v[8];
#pragma unroll
            for (int kk = 0; kk < 8; ++kk)
                v[kk] = fmaxf(s[kk] + sbias[c * 8 + kk], 0.f) + rr[kk];
            float* hp = h + (size_t)d * 128 + c * 8;
            *reinterpret_cast<float4*>(hp)     = make_float4(v[0], v[1], v[2], v[3]);
            *reinterpret_cast<float4*>(hp + 4) = make_float4(v[4], v[5], v[6], v[7]);
#pragma unroll
            for (int kk = 0; kk < 8; ++kk) {
                atomicAdd(&cs1[c * 8 + kk], v[kk]);
                atomicAdd(&cs2[c * 8 + kk], v[kk] * v[kk]);
            }
        }
    }
    __syncthreads();
    if (threadIdx.x < 128) {
        atomicAdd(&colsum[threadIdx.x], cs1[threadIdx.x]);
        atomicAdd(&colsumsq[threadIdx.x], cs2[threadIdx.x]);
    }
}

// ---------------- K6: BN apply + unpermute to natural cols -----------------
__global__ void k_bn(float* __restrict__ h, const float* __restrict__ colsum,
                     const float* __restrict__ colsumsq, const float* __restrict__ gamma,
                     const float* __restrict__ beta) {
    __shared__ float sc[128], sh[128], tile[8][128];
    int t = threadIdx.x;
    if (t < 128) {
        int n = unperm(t);
        float m = colsum[t] * (1.f / N_NODES);
        float var = colsumsq[t] * (1.f / N_NODES) - m * m;
        float s = gamma[n] * rsqrtf(var + 1e-5f);
        sc[t] = s;
        sh[t] = beta[n] - m * s;
    }
    __syncthreads();
    int r = t >> 5;
    int p0 = (t & 31) * 4;
    int n0 = (p0 & 64) + ((p0 >> 2) & 15);
    for (int row0 = blockIdx.x * 8; row0 < N_NODES; row0 += gridDim.x * 8) {
        int row = row0 + r;
        float4 v = make_float4(0.f, 0.f, 0.f, 0.f);
        if (row < N_NODES) v = *reinterpret_cast<float4*>(h + (size_t)row * 128 + p0);
        v.x = v.x * sc[p0] + sh[p0];
        v.y = v.y * sc[p0 + 1] + sh[p0 + 1];
        v.z = v.z * sc[p0 + 2] + sh[p0 + 2];
        v.w = v.w * sc[p0 + 3] + sh[p0 + 3];
        tile[r][n0]      = v.x;
        tile[r][n0 + 16] = v.y;
        tile[r][n0 + 32] = v.z;
        tile[r][n0 + 48] = v.w;
        __syncthreads();
        if (row < N_NODES)
            *reinterpret_cast<float4*>(h + (size_t)row * 128 + p0) =
                *reinterpret_cast<float4*>(&tile[r][p0]);
        __syncthreads();
    }
}

extern "C" void kernel_launch(void* const* d_in, const int* in_sizes, int n_in,
                              void* d_out, int out_size, void* d_ws, size_t ws_size,
                              hipStream_t stream) {
    (void)in_sizes; (void)n_in; (void)out_size; (void)ws_size;
    const float* node_feats = (const float*)d_in[0];
    const int* src    = (const int*)d_in[1];
    const int* dst    = (const int*)d_in[2];
    const int* etype  = (const int*)d_in[3];
    const float* norm = (const float*)d_in[4];
    const float* basis = (const float*)d_in[5];
    const float* comp  = (const float*)d_in[6];
    const float* h_bias = (const float*)d_in[7];
    const float* W_res  = (const float*)d_in[8];
    const float* b_res  = (const float*)d_in[9];
    const float* gamma  = (const float*)d_in[10];
    const float* beta   = (const float*)d_in[11];

    char* ws = (char*)d_ws;
    float* colsum   = (float*)(ws + 0);            // 512
    float* colsumsq = (float*)(ws + 512);          // 512
    int* ntiles_p   = (int*)(ws + 1024);           // 64
    int* cntA       = (int*)(ws + 1088);           // 628 -> pad 1792
    int* gh3        = (int*)(ws + 1792);           // 41600 -> 43392
    int* gh2        = (int*)(ws + 43392);          // 80000 -> 123392 [memset end]
    int* segAll     = (int*)(ws + 123392);         // 41604 -> 164996 pad 165056
    int* seg        = (int*)(ws + 165056);         // 80004 -> 245060 pad 245120
    int* tile_r     = (int*)(ws + 245120);         // 40960 -> 286080
    int* tile_start = (int*)(ws + 286080);         // 40960 -> 327040
    int* tile_len   = (int*)(ws + 327040);         // 40960 -> 368000
    unsigned short* Wt      = (unsigned short*)(ws + 368000);    // 2129920 -> 2497920
    unsigned short* Wrest   = (unsigned short*)(ws + 2497920);   // 32768   -> 2530688
    unsigned short* node_bf = (unsigned short*)(ws + 2530688);   // 5120000 -> 7650688
    int* srcp       = (int*)(ws + 7650688);        // 2560000 -> 10210688
    float* normp    = (float*)(ws + 10210688);     // 2560000 -> 12770688
    int* eidx       = (int*)(ws + 12770688);       // 2560000 -> 15330688
    u32x2* ebuf     = (u32x2*)(ws + 15330688);     // 5120000 -> 20450688
    float* resid    = (float*)(ws + 20450688);     // 10240000 -> 30690688
    const long T_BASE = 30690688L;                 // 16B aligned
    float* W32      = (float*)(ws + T_BASE);       // aliased: dead before conv
    unsigned short* t_buf = (unsigned short*)(ws + T_BASE);      // 163.84 MB
    float* hacc = (float*)d_out;

    hipMemsetAsync(ws, 0, 123392, stream);         // colsum..gh2
    k_prep1<<<2884, 256, 0, stream>>>(comp, basis, W32, etype, dst, gh3, gh2,
                                      node_feats, node_bf);
    k_prep3<<<384, 256, 0, stream>>>(gh3, segAll, gh2, seg, W32, Wt, W_res, Wrest);
    k_scatterA<<<250, 256, 0, stream>>>(etype, src, dst, norm, seg, cntA, ebuf);
    k_scatterB<<<160, 1024, 0, stream>>>(ebuf, seg, segAll, srcp, normp, eidx,
                                         ntiles_p, tile_r, tile_start, tile_len);
    k_conv_gemm<<<NB_RESID + MAX_TILES, 256, 0, stream>>>(
        tile_r, tile_start, tile_len, ntiles_p, srcp, normp, node_bf,
        Wt, Wrest, b_res, t_buf, resid);
    k_reduce_fused<<<2500, 256, 0, stream>>>(t_buf, seg, eidx, resid,
                                             h_bias, hacc, colsum, colsumsq);
    k_bn<<<2500, 256, 0, stream>>>(hacc, colsum, colsumsq, gamma, beta);
}